// Round 13
// baseline (477.601 us; speedup 1.0000x reference)
//
#include <hip/hip_runtime.h>

// LUT layer: out[b,o] = sum_d weights[d, idx[b,d], o]
// R13: LDS-staged streaming gather, execution-fixed vs r12:
//   512 blocks (2/CU), f32 LDS dbuf (64KB), idx in registers, full unroll.
//   Block = (512 batches, 32 dets, 32-out slice). Per det: stream 32KB f32
//   slice -> LDS, serve 512 random row-reads from LDS. Global traffic
//   512MB (vs 1GB direct r11 = 62us L2-request-bound).

typedef float f32x4 __attribute__((ext_vector_type(4)));

#define B_TOT   2048
#define N_IN    1024
#define N_DET   512
#define N_ANCH  8
#define N_OUT   256
#define DET_BYTES 262144        // 256 ch * 256 f32 * 4B

#define IDX_BYTES   ((size_t)B_TOT * N_DET)                  // 1 MB
#define NDG   16
#define PART2_BYTES ((size_t)NDG * B_TOT * N_OUT * 4)        // 32 MB

// old-path constants (fallback)
#define DET_G 8
#define DPG   (N_DET/DET_G)
#define BT2   32
#define PART_BYTES ((size_t)DET_G * B_TOT * N_OUT * 4)       // 16 MB

// ---------------- K1: compute LUT indices ----------------
__global__ __launch_bounds__(256) void lut_idx_kernel(
    const float* __restrict__ x,
    const int*   __restrict__ anchors,
    unsigned char* __restrict__ idx_out)
{
    __shared__ unsigned char bits[N_IN];
    const int b = blockIdx.x;
    const int t = threadIdx.x;

    const float4* xg = reinterpret_cast<const float4*>(x + (size_t)b * N_IN);
    float4 v = xg[t];
    bits[t * 4 + 0] = v.x > 0.0f;
    bits[t * 4 + 1] = v.y > 0.0f;
    bits[t * 4 + 2] = v.z > 0.0f;
    bits[t * 4 + 3] = v.w > 0.0f;
    __syncthreads();

    #pragma unroll
    for (int k = 0; k < N_DET / 256; ++k) {
        int d = t + k * 256;
        const int4* a4 = reinterpret_cast<const int4*>(anchors + d * N_ANCH);
        int4 a0 = a4[0];
        int4 a1 = a4[1];
        unsigned idx = 0;
        idx |= (unsigned)bits[a0.x];
        idx |= (unsigned)bits[a0.y] << 1;
        idx |= (unsigned)bits[a0.z] << 2;
        idx |= (unsigned)bits[a0.w] << 3;
        idx |= (unsigned)bits[a1.x] << 4;
        idx |= (unsigned)bits[a1.y] << 5;
        idx |= (unsigned)bits[a1.z] << 6;
        idx |= (unsigned)bits[a1.w] << 7;
        idx_out[(size_t)b * N_DET + d] = (unsigned char)idx;
    }
}

// ---------------- K2: LDS-staged streaming gather (512 thr, 2/CU) --------
__global__ __launch_bounds__(512, 4) void lut_gather3(
    const unsigned char* __restrict__ idx,
    const float* __restrict__ weights,
    float* __restrict__ partial)
{
    __shared__ f32x4 buf[2][2048];       // 2 x 32 KB (256 ch x 8 f32x4)

    const int bid   = blockIdx.x;        // 512 blocks
    const int chunk = bid >> 7;          // 4 batch chunks
    const int dg    = (bid >> 3) & 15;   // 16 det groups
    const int os    = bid & 7;           // 8 out slices (== XCD)
    const int b0    = chunk * 512;
    const int d0    = dg * 32;
    const int o0    = os * 32;

    const int t = threadIdx.x;

    // this thread's batch: its 32 idx bytes (dets d0..d0+31) -> 8 dwords
    unsigned iw[8];
    {
        const uint4* ip = reinterpret_cast<const uint4*>(
            idx + (size_t)(b0 + t) * N_DET + d0);
        uint4 va = ip[0], vb = ip[1];
        iw[0] = va.x; iw[1] = va.y; iw[2] = va.z; iw[3] = va.w;
        iw[4] = vb.x; iw[5] = vb.y; iw[6] = vb.z; iw[7] = vb.w;
    }

    __amdgpu_buffer_rsrc_t rs = __builtin_amdgcn_make_buffer_rsrc(
        (void*)weights, (short)0, (int)((size_t)N_DET * DET_BYTES), 0x00020000);

    // staging role: channel ch = t>>1, half h = t&1 (64B each)
    const int ch = t >> 1;
    const int h  = t & 1;
    const int vb_off = ch * 1024 + o0 * 4 + h * 64;   // bytes within det slab
    const int sst = ch & 7;                            // staging swizzle

    f32x4 rr[4];
    #pragma unroll
    for (int i = 0; i < 4; ++i) {
        auto rv = __builtin_amdgcn_raw_buffer_load_b128(
            rs, vb_off + i * 16, d0 * DET_BYTES, 1);
        rr[i] = __builtin_bit_cast(f32x4, rv);
    }

    f32x4 acc[8];
    #pragma unroll
    for (int j = 0; j < 8; ++j) acc[j] = (f32x4){0.f, 0.f, 0.f, 0.f};

    #pragma unroll
    for (int d = 0; d < 32; ++d) {
        const int cur = d & 1;
        // write staged slice to LDS (word w stored at position w ^ (ch&7))
        #pragma unroll
        for (int i = 0; i < 4; ++i)
            buf[cur][ch * 8 + ((h * 4 + i) ^ sst)] = rr[i];
        if (d + 1 < 32) {  // prefetch next det slice
            const int soff = (d0 + d + 1) * DET_BYTES;
            #pragma unroll
            for (int i = 0; i < 4; ++i) {
                auto rv = __builtin_amdgcn_raw_buffer_load_b128(
                    rs, vb_off + i * 16, soff, 1);
                rr[i] = __builtin_bit_cast(f32x4, rv);
            }
        }
        __syncthreads();   // buf[cur] ready; prior reads of buf[cur] done (d-2)

        // this thread's channel for det d (static reg index: loop unrolled)
        const unsigned c = (iw[d >> 2] >> (8 * (d & 3))) & 0xFFu;
        const int cs = (int)(c & 7u);
        const int cb = (int)c * 8;
        #pragma unroll
        for (int j = 0; j < 8; ++j)
            acc[j] += buf[cur][cb + (j ^ cs)];
    }

    // partial[dg][b][o0 + 4j .. 4j+3]
    f32x4* P4 = reinterpret_cast<f32x4*>(partial);
    const size_t pb = ((size_t)dg * B_TOT + b0 + t) * 64 + os * 8;
    #pragma unroll
    for (int j = 0; j < 8; ++j)
        __builtin_nontemporal_store(acc[j], &P4[pb + j]);
}

// ---------------- K3: reduce partials ----------------
template <int NG>
__global__ __launch_bounds__(256) void lut_reduce_kernel(
    const float* __restrict__ partial,
    float* __restrict__ out)
{
    const size_t i = (size_t)blockIdx.x * 256 + threadIdx.x; // over 2048*64 f4
    const f32x4* P4 = reinterpret_cast<const f32x4*>(partial);
    f32x4 s = (f32x4){0.f, 0.f, 0.f, 0.f};
    #pragma unroll
    for (int g = 0; g < NG; ++g) {
        f32x4 v = __builtin_nontemporal_load(&P4[(size_t)g * (B_TOT * 64) + i]);
        s += v;
    }
    reinterpret_cast<f32x4*>(out)[i] = s;
}

// ---------------- old direct gather (r11, 62us) as fallback ----------------
__global__ __launch_bounds__(256, 2) void lut_gather_kernel(
    const unsigned char* __restrict__ idx,
    const float* __restrict__ weights,
    float* __restrict__ partial)
{
    const int bid = blockIdx.x;
    const int g   = bid & (DET_G - 1);
    const int bc  = bid >> 3;
    const int b0  = bc * BT2;
    const int d0  = g * DPG;

    __shared__ unsigned char idx_s[DPG][BT2];

    const int t = threadIdx.x;
    {
        int r  = t >> 3;
        int cc = t & 7;
        uint2 v = *reinterpret_cast<const uint2*>(
            idx + (size_t)(b0 + r) * N_DET + d0 + cc * 8);
        unsigned char* bs = (unsigned char*)&v;
        #pragma unroll
        for (int i = 0; i < 8; ++i) idx_s[cc * 8 + i][r] = bs[i];
    }
    __syncthreads();

    const int wave = t >> 6;
    const int lane = t & 63;
    const int lane16 = lane * 16;

    f32x4 acc[8];
    #pragma unroll
    for (int j = 0; j < 8; ++j) acc[j] = (f32x4){0.f, 0.f, 0.f, 0.f};

    __amdgpu_buffer_rsrc_t rs = __builtin_amdgcn_make_buffer_rsrc(
        (void*)(reinterpret_cast<const char*>(weights) + (size_t)d0 * DET_BYTES),
        (short)0, (int)(DPG * DET_BYTES), 0x00020000);

    unsigned w0 = __builtin_amdgcn_readfirstlane(
        *reinterpret_cast<const unsigned*>(&idx_s[0][wave * 8]));
    unsigned w1 = __builtin_amdgcn_readfirstlane(
        *reinterpret_cast<const unsigned*>(&idx_s[0][wave * 8 + 4]));

    #pragma unroll 2
    for (int d = 0; d < DPG; ++d) {
        const unsigned lo = w0, hi = w1;
        if (d + 1 < DPG) {
            w0 = __builtin_amdgcn_readfirstlane(
                *reinterpret_cast<const unsigned*>(&idx_s[d + 1][wave * 8]));
            w1 = __builtin_amdgcn_readfirstlane(
                *reinterpret_cast<const unsigned*>(&idx_s[d + 1][wave * 8 + 4]));
        }
        const int db = d * DET_BYTES;
        f32x4 r[8];
        #pragma unroll
        for (int j = 0; j < 4; ++j) {
            auto rv = __builtin_amdgcn_raw_buffer_load_b128(
                rs, lane16, db + (int)(((lo >> (8 * j)) & 0xFFu) << 10), 1);
            r[j] = __builtin_bit_cast(f32x4, rv);
        }
        #pragma unroll
        for (int j = 0; j < 4; ++j) {
            auto rv = __builtin_amdgcn_raw_buffer_load_b128(
                rs, lane16, db + (int)(((hi >> (8 * j)) & 0xFFu) << 10), 1);
            r[4 + j] = __builtin_bit_cast(f32x4, rv);
        }
        #pragma unroll
        for (int j = 0; j < 8; ++j)
            acc[j] += r[j];
    }

    f32x4* P4 = reinterpret_cast<f32x4*>(partial);
    #pragma unroll
    for (int j = 0; j < 8; ++j) {
        size_t b = (size_t)b0 + wave * 8 + j;
        __builtin_nontemporal_store(acc[j],
            &P4[((size_t)g * B_TOT + b) * 64 + lane]);
    }
}

// ---------------- last-resort monolithic fallback ----------------
#define BT 4
__global__ __launch_bounds__(256) void lut_fused_kernel(
    const float* __restrict__ x,
    const int*   __restrict__ anchors,
    const float* __restrict__ weights,
    float*       __restrict__ out)
{
    __shared__ float x_s[BT][N_IN];
    __shared__ int   idx_s[BT][N_DET];
    const int tid = threadIdx.x;
    const int b0  = blockIdx.x * BT;
    {
        const float4* xg = reinterpret_cast<const float4*>(x + (size_t)b0 * N_IN);
        float4*       xs = reinterpret_cast<float4*>(&x_s[0][0]);
        #pragma unroll
        for (int k = 0; k < BT; ++k) xs[tid + k * 256] = xg[tid + k * 256];
    }
    __syncthreads();
    #pragma unroll
    for (int k = 0; k < (BT * N_DET) / 256; ++k) {
        int p  = tid + k * 256;
        int d  = p & (N_DET - 1);
        int bt = p >> 9;
        const int4* a4 = reinterpret_cast<const int4*>(anchors + d * N_ANCH);
        int4 a0 = a4[0];
        int4 a1 = a4[1];
        int idx = 0;
        idx |= (x_s[bt][a0.x] > 0.0f) ? 1   : 0;
        idx |= (x_s[bt][a0.y] > 0.0f) ? 2   : 0;
        idx |= (x_s[bt][a0.z] > 0.0f) ? 4   : 0;
        idx |= (x_s[bt][a0.w] > 0.0f) ? 8   : 0;
        idx |= (x_s[bt][a1.x] > 0.0f) ? 16  : 0;
        idx |= (x_s[bt][a1.y] > 0.0f) ? 32  : 0;
        idx |= (x_s[bt][a1.z] > 0.0f) ? 64  : 0;
        idx |= (x_s[bt][a1.w] > 0.0f) ? 128 : 0;
        idx_s[bt][d] = idx;
    }
    __syncthreads();
    const int wave = tid >> 6;
    const int lane = tid & 63;
    float4 acc = make_float4(0.0f, 0.0f, 0.0f, 0.0f);
    const float4* W4 = reinterpret_cast<const float4*>(weights);
    #pragma unroll 8
    for (int d = 0; d < N_DET; ++d) {
        int idx = idx_s[wave][d];
        size_t row = (size_t)(d << 8) + (size_t)idx;
        float4 w = W4[row * 64 + lane];
        acc.x += w.x; acc.y += w.y; acc.z += w.z; acc.w += w.w;
    }
    float4* out4 = reinterpret_cast<float4*>(out + (size_t)(b0 + wave) * N_OUT);
    out4[lane] = acc;
}

extern "C" void kernel_launch(void* const* d_in, const int* in_sizes, int n_in,
                              void* d_out, int out_size, void* d_ws, size_t ws_size,
                              hipStream_t stream) {
    const float* x       = (const float*)d_in[0];
    const int*   anchors = (const int*)  d_in[1];
    const float* weights = (const float*)d_in[2];
    float*       out     = (float*)d_out;

    if (ws_size >= IDX_BYTES + PART2_BYTES) {
        unsigned char* idx_ws  = (unsigned char*)d_ws;
        float*         part_ws = (float*)((char*)d_ws + IDX_BYTES);

        lut_idx_kernel<<<dim3(B_TOT), dim3(256), 0, stream>>>(x, anchors, idx_ws);
        lut_gather3<<<dim3(512), dim3(512), 0, stream>>>(
            idx_ws, weights, part_ws);
        lut_reduce_kernel<16><<<dim3(B_TOT * N_OUT / 4 / 256), dim3(256), 0, stream>>>(
            part_ws, out);
    } else if (ws_size >= IDX_BYTES + PART_BYTES) {
        unsigned char* idx_ws  = (unsigned char*)d_ws;
        float*         part_ws = (float*)((char*)d_ws + IDX_BYTES);

        lut_idx_kernel<<<dim3(B_TOT), dim3(256), 0, stream>>>(x, anchors, idx_ws);
        lut_gather_kernel<<<dim3((B_TOT / BT2) * DET_G), dim3(256), 0, stream>>>(
            idx_ws, weights, part_ws);
        lut_reduce_kernel<8><<<dim3(B_TOT * N_OUT / 4 / 256), dim3(256), 0, stream>>>(
            part_ws, out);
    } else {
        lut_fused_kernel<<<dim3(B_TOT / BT), dim3(256), 0, stream>>>(
            x, anchors, weights, out);
    }
}